// Round 10
// baseline (160.599 us; speedup 1.0000x reference)
//
#include <hip/hip_runtime.h>
#include <hip/hip_bf16.h>
#include <stdint.h>

#define LOG2E 1.44269504088896340736f

typedef float f32x4 __attribute__((ext_vector_type(4)));
typedef float f32x16 __attribute__((ext_vector_type(16)));
typedef __bf16 bf16x8 __attribute__((ext_vector_type(8)));

__device__ __forceinline__ void g2lds16(const void* g, void* l) {
  __builtin_amdgcn_global_load_lds(
      (__attribute__((address_space(1))) unsigned int*)g,
      (__attribute__((address_space(3))) unsigned int*)l,
      16, 0, 0);
}

__device__ __forceinline__ unsigned short f2bf_u(float f) {
  __bf16 h = (__bf16)f;
  return __builtin_bit_cast(unsigned short, h);
}

// ---------------------------------------------------------------------------
// fused_prep: 640 blocks. pid<512: prep_hidden (barrier-free, 4 waves x 4
// rows, XCD-colocated row mapping). pid>=512: prep_w grid-stride bf16 cast.
// (unchanged — measured-good)
// ---------------------------------------------------------------------------
__global__ void __launch_bounds__(256) fused_prep(
    const float* __restrict__ hidden, const float* __restrict__ U,
    const float* __restrict__ V, const float* __restrict__ vw,
    unsigned short* __restrict__ hbf, unsigned short* __restrict__ wbf,
    float* __restrict__ aL, float* __restrict__ vArr) {
  int tid = threadIdx.x;
  int pid = blockIdx.x;
  if (pid < 512) {
    int lane = tid & 63, w = tid >> 6;
    int xcd = pid & 7, idx = pid >> 3;
    int row0 = (xcd << 10) + (idx * 4 + w) * 4;
    float4 u4[4], v4[4];
#pragma unroll
    for (int c = 0; c < 4; ++c) {
      u4[c] = *(const float4*)&U[c * 256 + lane * 4];
      v4[c] = *(const float4*)&V[c * 256 + lane * 4];
    }
    float u_t = U[1024], v_t = V[1024];
    float su[4], sv[4];
#pragma unroll
    for (int r = 0; r < 4; ++r) {
      const float* hr = hidden + (size_t)(row0 + r) * 1024;
      unsigned short* hb = hbf + (size_t)(row0 + r) * 1024;
      float ssu = 0.f, ssv = 0.f;
#pragma unroll
      for (int c = 0; c < 4; ++c) {
        float4 x = *(const float4*)&hr[c * 256 + lane * 4];
        ushort4 o;
        o.x = f2bf_u(x.x); o.y = f2bf_u(x.y); o.z = f2bf_u(x.z); o.w = f2bf_u(x.w);
        *(ushort4*)&hb[c * 256 + lane * 4] = o;
        ssu += x.x * u4[c].x + x.y * u4[c].y + x.z * u4[c].z + x.w * u4[c].w;
        ssv += x.x * v4[c].x + x.y * v4[c].y + x.z * v4[c].z + x.w * v4[c].w;
      }
      su[r] = ssu; sv[r] = ssv;
    }
#pragma unroll
    for (int off = 1; off < 64; off <<= 1) {
#pragma unroll
      for (int r = 0; r < 4; ++r) {
        su[r] += __shfl_xor(su[r], off);
        sv[r] += __shfl_xor(sv[r], off);
      }
    }
    if (lane < 4) {
      int r = lane;
      float sur = (r == 0) ? su[0] : (r == 1) ? su[1] : (r == 2) ? su[2] : su[3];
      float svr = (r == 0) ? sv[0] : (r == 1) ? sv[1] : (r == 2) ? sv[2] : sv[3];
      aL[row0 + r] = (sur + u_t) * 0.125f * LOG2E;
      vArr[row0 + r] = svr + v_t;
    }
  } else {
    int wp = pid - 512;  // [0,128)
#pragma unroll
    for (int it = 0; it < 8; ++it) {
      int idx = (wp * 256 + tid) * 4 + it * 131072;
      float4 x = *(const float4*)&vw[idx];
      ushort4 o;
      o.x = f2bf_u(x.x); o.y = f2bf_u(x.y); o.z = f2bf_u(x.z); o.w = f2bf_u(x.w);
      *(ushort4*)&wbf[idx] = o;
    }
  }
}

// ---------------------------------------------------------------------------
// gemm_stats: pid < statsBlocks -> statsP (barrier-free); pid >= statsBlocks
// -> gemm_vl, 128x128 tile, BK=128, 16-chunk XOR swizzle, XCD-colocated,
// 32x32x16 MFMA (2x2 tiles/wave, 8cyc/MFMA pipe rate > 16x16 rate).
// A/B frag: m=lane&31, k=(lane>>5)*8+j. C/D: col=lane&31,
// row=(reg&3)+8*(reg>>2)+4*(lane>>5)  [verified m74/m101].
// ---------------------------------------------------------------------------
__global__ void __launch_bounds__(256) gemm_stats(
    const unsigned short* __restrict__ hbf, const unsigned short* __restrict__ wbf,
    const float* __restrict__ bias, unsigned short* __restrict__ vlt,
    const float* __restrict__ aL, const float* __restrict__ vArr,
    const float* __restrict__ mask, unsigned short* __restrict__ P,
    int statsBlocks) {
  __shared__ __align__(16) char sA[128 * 256];
  __shared__ __align__(16) char sB[128 * 256];
  int tid = threadIdx.x;
  int pid = blockIdx.x;
  if (pid >= statsBlocks) {
    int g = pid - statsBlocks;
    int lane = tid & 63, wave = tid >> 6;
    int xcd = g & 7, kk = g >> 3;
    int m0 = (xcd * 8 + (kk >> 3)) * 128;
    int n0 = (kk & 7) * 128;
    int rl = lane >> 4, pc = lane & 15;
    int wr = wave >> 1, wc = wave & 1;
    int ln31 = lane & 31, half = lane >> 5;
    f32x16 acc[2][2] = {};
    for (int k0 = 0; k0 < 1024; k0 += 128) {
      __syncthreads();
#pragma unroll
      for (int ii = 0; ii < 8; ++ii) {
        int rb = wave * 32 + ii * 4;
        int r = rb + rl;
        int gc = pc ^ (r & 15);
        g2lds16(hbf + (size_t)(m0 + r) * 1024 + k0 + gc * 8, sA + rb * 256);
        g2lds16(wbf + (size_t)(n0 + r) * 1024 + k0 + gc * 8, sB + rb * 256);
      }
      __syncthreads();
#pragma unroll
      for (int ks = 0; ks < 8; ++ks) {
        bf16x8 af[2], bfr[2];
#pragma unroll
        for (int mt = 0; mt < 2; ++mt) {
          int r = wr * 64 + mt * 32 + ln31;
          int ch = (ks * 2 + half) ^ (r & 15);
          af[mt] = *(const bf16x8*)(sA + r * 256 + ch * 16);
        }
#pragma unroll
        for (int nt = 0; nt < 2; ++nt) {
          int r = wc * 64 + nt * 32 + ln31;
          int ch = (ks * 2 + half) ^ (r & 15);
          bfr[nt] = *(const bf16x8*)(sB + r * 256 + ch * 16);
        }
#pragma unroll
        for (int mt = 0; mt < 2; ++mt)
#pragma unroll
          for (int nt = 0; nt < 2; ++nt)
            acc[mt][nt] = __builtin_amdgcn_mfma_f32_32x32x16_bf16(
                af[mt], bfr[nt], acc[mt][nt], 0, 0, 0);
      }
    }
#pragma unroll
    for (int nt = 0; nt < 2; ++nt) {
      int j = n0 + wc * 64 + nt * 32 + ln31;
      float bj = bias[j];
#pragma unroll
      for (int mt = 0; mt < 2; ++mt) {
        f32x16 a = acc[mt][nt];
#pragma unroll
        for (int gg = 0; gg < 4; ++gg) {
          int i = m0 + wr * 64 + mt * 32 + gg * 8 + half * 4;
          ushort4 o;
          o.x = f2bf_u(a[gg * 4 + 0] + bj);
          o.y = f2bf_u(a[gg * 4 + 1] + bj);
          o.z = f2bf_u(a[gg * 4 + 2] + bj);
          o.w = f2bf_u(a[gg * 4 + 3] + bj);
          *(ushort4*)&vlt[(size_t)j * 8192 + i] = o;
        }
      }
    }
  } else {
    // ---- statsP path: barrier-free, 4 waves x 8 rows, XCD-colocated ----
    int b = pid;
    int lane = tid & 63, w = tid >> 6;
    int xcd = b & 7, idx = b >> 3;               // idx in [0,32)
    int row0 = (xcd << 10) + (idx * 4 + w) * 8;  // 8 rows per wave
    int tb = (row0 >> 11) << 11;
    float4 va[8], ma[8];
#pragma unroll
    for (int c = 0; c < 4; ++c) {
      int t = c * 512 + lane * 8;
      va[2 * c]     = *(const float4*)&vArr[tb + t];
      va[2 * c + 1] = *(const float4*)&vArr[tb + t + 4];
      float4 m0v = *(const float4*)&mask[tb + t];
      float4 m1v = *(const float4*)&mask[tb + t + 4];
      ma[2 * c].x = m0v.x * LOG2E; ma[2 * c].y = m0v.y * LOG2E;
      ma[2 * c].z = m0v.z * LOG2E; ma[2 * c].w = m0v.w * LOG2E;
      ma[2 * c + 1].x = m1v.x * LOG2E; ma[2 * c + 1].y = m1v.y * LOG2E;
      ma[2 * c + 1].z = m1v.z * LOG2E; ma[2 * c + 1].w = m1v.w * LOG2E;
    }
#pragma unroll
    for (int r = 0; r < 8; ++r) {
      int row = row0 + r;
      float a = aL[row];
      float s[32];
#pragma unroll
      for (int qq = 0; qq < 8; ++qq) {
        s[qq * 4 + 0] = fmaf(a, va[qq].x, ma[qq].x);
        s[qq * 4 + 1] = fmaf(a, va[qq].y, ma[qq].y);
        s[qq * 4 + 2] = fmaf(a, va[qq].z, ma[qq].z);
        s[qq * 4 + 3] = fmaf(a, va[qq].w, ma[qq].w);
      }
      float mx = s[0];
#pragma unroll
      for (int u = 1; u < 32; ++u) mx = fmaxf(mx, s[u]);
#pragma unroll
      for (int off = 1; off < 64; off <<= 1) mx = fmaxf(mx, __shfl_xor(mx, off));
      float z = 0.f;
#pragma unroll
      for (int u = 0; u < 32; ++u) {
        s[u] = __builtin_amdgcn_exp2f(s[u] - mx);
        z += s[u];
      }
#pragma unroll
      for (int off = 1; off < 64; off <<= 1) z += __shfl_xor(z, off);
      float iz = __builtin_amdgcn_rcpf(z);
      unsigned short* pr = P + (size_t)row * 2048;
#pragma unroll
      for (int c = 0; c < 4; ++c) {
        bf16x8 o;
#pragma unroll
        for (int u = 0; u < 8; ++u) o[u] = (__bf16)(iz * s[c * 8 + u]);
        *(bf16x8*)&pr[c * 512 + lane * 8] = o;
      }
    }
  }
}

// ---------------------------------------------------------------------------
// attn: C = P' @ VL^T-slice, K=2048, BK=128, 512 blocks, 128x128 tile,
// 32x32x16 MFMA (2x2 tiles/wave), 16-chunk XOR swizzle, XCD swizzle.
// ---------------------------------------------------------------------------
__global__ void __launch_bounds__(256) attn(
    const unsigned short* __restrict__ p, const unsigned short* __restrict__ vlt,
    float* __restrict__ out) {
  __shared__ __align__(16) char sA[128 * 256];
  __shared__ __align__(16) char sB[128 * 256];
  int tid = threadIdx.x;
  int lane = tid & 63, wave = tid >> 6;
  int pid = blockIdx.x;
  int xcd = pid & 7, kk = pid >> 3;
  int i0 = (xcd * 8 + (kk >> 3)) * 128;  // s-row tile (batch-major)
  int h0 = (kk & 7) * 128;               // h tile
  int b = i0 >> 11;
  size_t toff = (size_t)b << 11;
  int rl = lane >> 4, pc = lane & 15;
  int wr = wave >> 1, wc = wave & 1;
  int ln31 = lane & 31, half = lane >> 5;
  f32x16 acc[2][2] = {};
  for (int k0 = 0; k0 < 2048; k0 += 128) {
    __syncthreads();
#pragma unroll
    for (int ii = 0; ii < 8; ++ii) {
      int rb = wave * 32 + ii * 4;
      int r = rb + rl;
      int gc = pc ^ (r & 15);
      g2lds16(p + (size_t)(i0 + r) * 2048 + k0 + gc * 8, sA + rb * 256);
      g2lds16(vlt + (size_t)(h0 + r) * 8192 + toff + k0 + gc * 8, sB + rb * 256);
    }
    __syncthreads();
#pragma unroll
    for (int ks = 0; ks < 8; ++ks) {
      bf16x8 af[2], bfr[2];
#pragma unroll
      for (int mt = 0; mt < 2; ++mt) {
        int r = wr * 64 + mt * 32 + ln31;
        int ch = (ks * 2 + half) ^ (r & 15);
        af[mt] = *(const bf16x8*)(sA + r * 256 + ch * 16);
      }
#pragma unroll
      for (int nt = 0; nt < 2; ++nt) {
        int r = wc * 64 + nt * 32 + ln31;
        int ch = (ks * 2 + half) ^ (r & 15);
        bfr[nt] = *(const bf16x8*)(sB + r * 256 + ch * 16);
      }
#pragma unroll
      for (int mt = 0; mt < 2; ++mt)
#pragma unroll
        for (int nt = 0; nt < 2; ++nt)
          acc[mt][nt] = __builtin_amdgcn_mfma_f32_32x32x16_bf16(
              af[mt], bfr[nt], acc[mt][nt], 0, 0, 0);
    }
  }
#pragma unroll
  for (int nt = 0; nt < 2; ++nt) {
    int h = h0 + wc * 64 + nt * 32 + ln31;
#pragma unroll
    for (int mt = 0; mt < 2; ++mt) {
      f32x16 a = acc[mt][nt];
#pragma unroll
      for (int gg = 0; gg < 4; ++gg) {
        int gi = i0 + wr * 64 + mt * 32 + gg * 8 + half * 4;
        out[(size_t)(gi + 0) * 1024 + h] = a[gg * 4 + 0];
        out[(size_t)(gi + 1) * 1024 + h] = a[gg * 4 + 1];
        out[(size_t)(gi + 2) * 1024 + h] = a[gg * 4 + 2];
        out[(size_t)(gi + 3) * 1024 + h] = a[gg * 4 + 3];
      }
    }
  }
}

// ---------------------------------------------------------------------------
// Layout A (ws >= 69.3 MB, 3 launches; P disjoint so statsP overlaps gemm):
//   hbf 0..16MB | wbf 16..18MB | vlt 18..34.8MB | P 34.8..68.3MB | aL,vArr
// Layout B (fallback, 4 launches; P overlaps dead hbf/wbf).
// ---------------------------------------------------------------------------
extern "C" void kernel_launch(void* const* d_in, const int* in_sizes, int n_in,
                              void* d_out, int out_size, void* d_ws, size_t ws_size,
                              hipStream_t stream) {
  const float* hidden = (const float*)d_in[0];
  const float* mask   = (const float*)d_in[1];
  const float* vw     = (const float*)d_in[2];
  const float* vb     = (const float*)d_in[3];
  const float* U      = (const float*)d_in[4];
  const float* V      = (const float*)d_in[5];
  float* out = (float*)d_out;
  char* ws = (char*)d_ws;

  if (ws_size >= 69271552ull) {
    unsigned short* hbf = (unsigned short*)ws;
    unsigned short* wbf = (unsigned short*)(ws + 16777216);
    unsigned short* vlt = (unsigned short*)(ws + 18874368);
    unsigned short* P   = (unsigned short*)(ws + 35651584);
    float* aL   = (float*)(ws + 69206016);
    float* vArr = aL + 8192;
    fused_prep<<<640, 256, 0, stream>>>(hidden, U, V, vw, hbf, wbf, aL, vArr);
    gemm_stats<<<768, 256, 0, stream>>>(hbf, wbf, vb, vlt, aL, vArr, mask, P, 256);
    attn<<<512, 256, 0, stream>>>(P, vlt, out);
  } else {
    unsigned short* hbf = (unsigned short*)ws;
    unsigned short* wbf = (unsigned short*)(ws + 16777216);
    unsigned short* P   = (unsigned short*)ws;               // overlaps dead hbf/wbf
    unsigned short* vlt = (unsigned short*)(ws + 33554432);
    float* aL   = (float*)(ws + 50331648);
    float* vArr = aL + 8192;
    fused_prep<<<640, 256, 0, stream>>>(hidden, U, V, vw, hbf, wbf, aL, vArr);
    gemm_stats<<<512, 256, 0, stream>>>(hbf, wbf, vb, vlt, aL, vArr, mask, P, 0);
    gemm_stats<<<256, 256, 0, stream>>>(hbf, wbf, vb, vlt, aL, vArr, mask, P, 256);
    attn<<<512, 256, 0, stream>>>(P, vlt, out);
  }
}

// Round 11
// 159.018 us; speedup vs baseline: 1.0099x; 1.0099x over previous
//
#include <hip/hip_runtime.h>
#include <hip/hip_bf16.h>
#include <stdint.h>

#define LOG2E 1.44269504088896340736f

typedef float f32x4 __attribute__((ext_vector_type(4)));
typedef __bf16 bf16x8 __attribute__((ext_vector_type(8)));

__device__ __forceinline__ void g2lds16(const void* g, void* l) {
  __builtin_amdgcn_global_load_lds(
      (__attribute__((address_space(1))) unsigned int*)g,
      (__attribute__((address_space(3))) unsigned int*)l,
      16, 0, 0);
}

__device__ __forceinline__ unsigned short f2bf_u(float f) {
  __bf16 h = (__bf16)f;
  return __builtin_bit_cast(unsigned short, h);
}

// ---------------------------------------------------------------------------
// fused_prep: 512 blocks, 4 waves x 4 rows each (barrier-free, xor-butterfly
// reductions, XCD-colocated row map). Each block also converts 2048 vw elems
// to bf16 (folds the old 128-block prep_w tail into the same launch).
// ---------------------------------------------------------------------------
__global__ void __launch_bounds__(256) fused_prep(
    const float* __restrict__ hidden, const float* __restrict__ U,
    const float* __restrict__ V, const float* __restrict__ vw,
    unsigned short* __restrict__ hbf, unsigned short* __restrict__ wbf,
    float* __restrict__ aL, float* __restrict__ vArr) {
  int tid = threadIdx.x;
  int pid = blockIdx.x;
  int lane = tid & 63, w = tid >> 6;
  int xcd = pid & 7, idx = pid >> 3;
  int row0 = (xcd << 10) + (idx * 4 + w) * 4;
  float4 u4[4], v4[4];
#pragma unroll
  for (int c = 0; c < 4; ++c) {
    u4[c] = *(const float4*)&U[c * 256 + lane * 4];
    v4[c] = *(const float4*)&V[c * 256 + lane * 4];
  }
  float u_t = U[1024], v_t = V[1024];
  float su[4], sv[4];
#pragma unroll
  for (int r = 0; r < 4; ++r) {
    const float* hr = hidden + (size_t)(row0 + r) * 1024;
    unsigned short* hb = hbf + (size_t)(row0 + r) * 1024;
    float ssu = 0.f, ssv = 0.f;
#pragma unroll
    for (int c = 0; c < 4; ++c) {
      float4 x = *(const float4*)&hr[c * 256 + lane * 4];
      ushort4 o;
      o.x = f2bf_u(x.x); o.y = f2bf_u(x.y); o.z = f2bf_u(x.z); o.w = f2bf_u(x.w);
      *(ushort4*)&hb[c * 256 + lane * 4] = o;
      ssu += x.x * u4[c].x + x.y * u4[c].y + x.z * u4[c].z + x.w * u4[c].w;
      ssv += x.x * v4[c].x + x.y * v4[c].y + x.z * v4[c].z + x.w * v4[c].w;
    }
    su[r] = ssu; sv[r] = ssv;
  }
#pragma unroll
  for (int off = 1; off < 64; off <<= 1) {
#pragma unroll
    for (int r = 0; r < 4; ++r) {
      su[r] += __shfl_xor(su[r], off);
      sv[r] += __shfl_xor(sv[r], off);
    }
  }
  if (lane < 4) {
    int r = lane;
    float sur = (r == 0) ? su[0] : (r == 1) ? su[1] : (r == 2) ? su[2] : su[3];
    float svr = (r == 0) ? sv[0] : (r == 1) ? sv[1] : (r == 2) ? sv[2] : sv[3];
    aL[row0 + r] = (sur + u_t) * 0.125f * LOG2E;
    vArr[row0 + r] = svr + v_t;
  }
  // vw -> bf16: block pid covers elems [pid*2048, pid*2048+2048)
#pragma unroll
  for (int it = 0; it < 2; ++it) {
    int base = pid * 2048 + it * 1024 + tid * 4;
    float4 x = *(const float4*)&vw[base];
    ushort4 o;
    o.x = f2bf_u(x.x); o.y = f2bf_u(x.y); o.z = f2bf_u(x.z); o.w = f2bf_u(x.w);
    *(ushort4*)&wbf[base] = o;
  }
}

// ---------------------------------------------------------------------------
// gemm_stats: pid < statsBlocks -> statsP (barrier-free, 4 waves x 8 rows),
// launched FIRST so the short stats work overlaps the gemm ramp. pid >=
// statsBlocks -> gemm_vl, 128x128 tile, BK=128 (8 barrier pairs), 16-chunk
// XOR swizzle (phys = chunk ^ (row&15)), XCD-colocated, 16x16x32 MFMA.
// (round-9 measured-best configuration)
// ---------------------------------------------------------------------------
__global__ void __launch_bounds__(256) gemm_stats(
    const unsigned short* __restrict__ hbf, const unsigned short* __restrict__ wbf,
    const float* __restrict__ bias, unsigned short* __restrict__ vlt,
    const float* __restrict__ aL, const float* __restrict__ vArr,
    const float* __restrict__ mask, unsigned short* __restrict__ P,
    int statsBlocks) {
  __shared__ __align__(16) char sA[128 * 256];
  __shared__ __align__(16) char sB[128 * 256];
  int tid = threadIdx.x;
  int pid = blockIdx.x;
  if (pid >= statsBlocks) {
    int g = pid - statsBlocks;
    int lane = tid & 63, wave = tid >> 6;
    int xcd = g & 7, kk = g >> 3;
    int m0 = (xcd * 8 + (kk >> 3)) * 128;
    int n0 = (kk & 7) * 128;
    int rl = lane >> 4, pc = lane & 15;
    int wr = wave >> 1, wc = wave & 1;
    int m_ = lane & 15, q = lane >> 4;
    f32x4 acc[4][4] = {};
    for (int k0 = 0; k0 < 1024; k0 += 128) {
      __syncthreads();
#pragma unroll
      for (int ii = 0; ii < 8; ++ii) {
        int rb = wave * 32 + ii * 4;
        int r = rb + rl;
        int gc = pc ^ (r & 15);
        g2lds16(hbf + (size_t)(m0 + r) * 1024 + k0 + gc * 8, sA + rb * 256);
        g2lds16(wbf + (size_t)(n0 + r) * 1024 + k0 + gc * 8, sB + rb * 256);
      }
      __syncthreads();
#pragma unroll
      for (int ks = 0; ks < 4; ++ks) {
        bf16x8 af[4], bfr[4];
#pragma unroll
        for (int i = 0; i < 4; ++i)
          af[i] = *(const bf16x8*)(sA + (wr * 64 + i * 16 + m_) * 256 + (((ks * 4 + q) ^ m_) * 16));
#pragma unroll
        for (int j = 0; j < 4; ++j)
          bfr[j] = *(const bf16x8*)(sB + (wc * 64 + j * 16 + m_) * 256 + (((ks * 4 + q) ^ m_) * 16));
#pragma unroll
        for (int i = 0; i < 4; ++i)
#pragma unroll
          for (int j = 0; j < 4; ++j)
            acc[i][j] = __builtin_amdgcn_mfma_f32_16x16x32_bf16(af[i], bfr[j], acc[i][j], 0, 0, 0);
      }
    }
#pragma unroll
    for (int jt = 0; jt < 4; ++jt) {
      int j = n0 + wc * 64 + jt * 16 + m_;
      float bj = bias[j];
#pragma unroll
      for (int it = 0; it < 4; ++it) {
        int i = m0 + wr * 64 + it * 16 + q * 4;
        f32x4 a = acc[it][jt];
        ushort4 o;
        o.x = f2bf_u(a.x + bj); o.y = f2bf_u(a.y + bj);
        o.z = f2bf_u(a.z + bj); o.w = f2bf_u(a.w + bj);
        *(ushort4*)&vlt[(size_t)j * 8192 + i] = o;
      }
    }
  } else {
    // ---- statsP path: barrier-free, 4 waves x 8 rows, XCD-colocated ----
    int b = pid;
    int lane = tid & 63, w = tid >> 6;
    int xcd = b & 7, idx = b >> 3;               // idx in [0,32)
    int row0 = (xcd << 10) + (idx * 4 + w) * 8;  // 8 rows per wave
    int tb = (row0 >> 11) << 11;
    float4 va[8], ma[8];
#pragma unroll
    for (int c = 0; c < 4; ++c) {
      int t = c * 512 + lane * 8;
      va[2 * c]     = *(const float4*)&vArr[tb + t];
      va[2 * c + 1] = *(const float4*)&vArr[tb + t + 4];
      float4 m0v = *(const float4*)&mask[tb + t];
      float4 m1v = *(const float4*)&mask[tb + t + 4];
      ma[2 * c].x = m0v.x * LOG2E; ma[2 * c].y = m0v.y * LOG2E;
      ma[2 * c].z = m0v.z * LOG2E; ma[2 * c].w = m0v.w * LOG2E;
      ma[2 * c + 1].x = m1v.x * LOG2E; ma[2 * c + 1].y = m1v.y * LOG2E;
      ma[2 * c + 1].z = m1v.z * LOG2E; ma[2 * c + 1].w = m1v.w * LOG2E;
    }
#pragma unroll
    for (int r = 0; r < 8; ++r) {
      int row = row0 + r;
      float a = aL[row];
      float s[32];
#pragma unroll
      for (int qq = 0; qq < 8; ++qq) {
        s[qq * 4 + 0] = fmaf(a, va[qq].x, ma[qq].x);
        s[qq * 4 + 1] = fmaf(a, va[qq].y, ma[qq].y);
        s[qq * 4 + 2] = fmaf(a, va[qq].z, ma[qq].z);
        s[qq * 4 + 3] = fmaf(a, va[qq].w, ma[qq].w);
      }
      float mx = s[0];
#pragma unroll
      for (int u = 1; u < 32; ++u) mx = fmaxf(mx, s[u]);
#pragma unroll
      for (int off = 1; off < 64; off <<= 1) mx = fmaxf(mx, __shfl_xor(mx, off));
      float z = 0.f;
#pragma unroll
      for (int u = 0; u < 32; ++u) {
        s[u] = __builtin_amdgcn_exp2f(s[u] - mx);
        z += s[u];
      }
#pragma unroll
      for (int off = 1; off < 64; off <<= 1) z += __shfl_xor(z, off);
      float iz = __builtin_amdgcn_rcpf(z);
      unsigned short* pr = P + (size_t)row * 2048;
#pragma unroll
      for (int c = 0; c < 4; ++c) {
        bf16x8 o;
#pragma unroll
        for (int u = 0; u < 8; ++u) o[u] = (__bf16)(iz * s[c * 8 + u]);
        *(bf16x8*)&pr[c * 512 + lane * 8] = o;
      }
    }
  }
}

// ---------------------------------------------------------------------------
// attn: C = P' @ VL^T-slice, K=2048, BK=128 (8 barrier pairs). 512 blocks
// (grid-limited 2/CU; 64KB LDS costs no occupancy), 128x128 tile, 16x16x32
// MFMA, 16-chunk XOR swizzle, XCD swizzle. (round-9 measured-best)
// ---------------------------------------------------------------------------
__global__ void __launch_bounds__(256) attn(
    const unsigned short* __restrict__ p, const unsigned short* __restrict__ vlt,
    float* __restrict__ out) {
  __shared__ __align__(16) char sA[128 * 256];
  __shared__ __align__(16) char sB[128 * 256];
  int tid = threadIdx.x;
  int lane = tid & 63, wave = tid >> 6;
  int pid = blockIdx.x;
  int xcd = pid & 7, kk = pid >> 3;
  int i0 = (xcd * 8 + (kk >> 3)) * 128;  // s-row tile (batch-major)
  int h0 = (kk & 7) * 128;               // h tile
  int b = i0 >> 11;
  size_t toff = (size_t)b << 11;
  int rl = lane >> 4, pc = lane & 15;
  int wr = wave >> 1, wc = wave & 1;
  int m_ = lane & 15, q = lane >> 4;
  f32x4 acc[4][4] = {};
  for (int k0 = 0; k0 < 2048; k0 += 128) {
    __syncthreads();
#pragma unroll
    for (int ii = 0; ii < 8; ++ii) {
      int rb = wave * 32 + ii * 4;
      int r = rb + rl;
      int gc = pc ^ (r & 15);
      g2lds16(p + (size_t)(i0 + r) * 2048 + k0 + gc * 8, sA + rb * 256);
      g2lds16(vlt + (size_t)(h0 + r) * 8192 + toff + k0 + gc * 8, sB + rb * 256);
    }
    __syncthreads();
#pragma unroll
    for (int ks = 0; ks < 4; ++ks) {
      bf16x8 af[4], bfr[4];
#pragma unroll
      for (int i = 0; i < 4; ++i)
        af[i] = *(const bf16x8*)(sA + (wr * 64 + i * 16 + m_) * 256 + (((ks * 4 + q) ^ m_) * 16));
#pragma unroll
      for (int j = 0; j < 4; ++j)
        bfr[j] = *(const bf16x8*)(sB + (wc * 64 + j * 16 + m_) * 256 + (((ks * 4 + q) ^ m_) * 16));
#pragma unroll
      for (int i = 0; i < 4; ++i)
#pragma unroll
        for (int j = 0; j < 4; ++j)
          acc[i][j] = __builtin_amdgcn_mfma_f32_16x16x32_bf16(af[i], bfr[j], acc[i][j], 0, 0, 0);
    }
  }
#pragma unroll
  for (int it = 0; it < 4; ++it) {
    int gi = i0 + wr * 64 + it * 16 + q * 4;
#pragma unroll
    for (int jt = 0; jt < 4; ++jt) {
      int h = h0 + wc * 64 + jt * 16 + m_;
      f32x4 a = acc[it][jt];
      out[(size_t)(gi + 0) * 1024 + h] = a.x;
      out[(size_t)(gi + 1) * 1024 + h] = a.y;
      out[(size_t)(gi + 2) * 1024 + h] = a.z;
      out[(size_t)(gi + 3) * 1024 + h] = a.w;
    }
  }
}

// ---------------------------------------------------------------------------
// Layout A (ws >= 69.3 MB, 3 launches; P disjoint so statsP overlaps gemm):
//   hbf 0..16MB | wbf 16..18MB | vlt 18..34.8MB | P 34.8..68.3MB | aL,vArr
// Layout B (fallback, 4 launches; P overlaps dead hbf/wbf).
// ---------------------------------------------------------------------------
extern "C" void kernel_launch(void* const* d_in, const int* in_sizes, int n_in,
                              void* d_out, int out_size, void* d_ws, size_t ws_size,
                              hipStream_t stream) {
  const float* hidden = (const float*)d_in[0];
  const float* mask   = (const float*)d_in[1];
  const float* vw     = (const float*)d_in[2];
  const float* vb     = (const float*)d_in[3];
  const float* U      = (const float*)d_in[4];
  const float* V      = (const float*)d_in[5];
  float* out = (float*)d_out;
  char* ws = (char*)d_ws;

  if (ws_size >= 69271552ull) {
    unsigned short* hbf = (unsigned short*)ws;
    unsigned short* wbf = (unsigned short*)(ws + 16777216);
    unsigned short* vlt = (unsigned short*)(ws + 18874368);
    unsigned short* P   = (unsigned short*)(ws + 35651584);
    float* aL   = (float*)(ws + 69206016);
    float* vArr = aL + 8192;
    fused_prep<<<512, 256, 0, stream>>>(hidden, U, V, vw, hbf, wbf, aL, vArr);
    gemm_stats<<<768, 256, 0, stream>>>(hbf, wbf, vb, vlt, aL, vArr, mask, P, 256);
    attn<<<512, 256, 0, stream>>>(P, vlt, out);
  } else {
    unsigned short* hbf = (unsigned short*)ws;
    unsigned short* wbf = (unsigned short*)(ws + 16777216);
    unsigned short* P   = (unsigned short*)ws;               // overlaps dead hbf/wbf
    unsigned short* vlt = (unsigned short*)(ws + 33554432);
    float* aL   = (float*)(ws + 50331648);
    float* vArr = aL + 8192;
    fused_prep<<<512, 256, 0, stream>>>(hidden, U, V, vw, hbf, wbf, aL, vArr);
    gemm_stats<<<512, 256, 0, stream>>>(hbf, wbf, vb, vlt, aL, vArr, mask, P, 0);
    gemm_stats<<<256, 256, 0, stream>>>(hbf, wbf, vb, vlt, aL, vArr, mask, P, 256);
    attn<<<512, 256, 0, stream>>>(P, vlt, out);
  }
}